// Round 8
// baseline (832.130 us; speedup 1.0000x reference)
//
#include <hip/hip_runtime.h>
#include <math.h>

#define CCH 32        // channels
#define NCH 224       // 7*C radial outputs
#define NIV 33        // PWL intervals
#define HRAD 32
#define ET 16         // nodes per epi block-iter
#define DG1 48        // blocks for degree counting sort (LDS-privatized)

// ---------------- CSR build ----------------

__global__ void hist_kernel(const int* __restrict__ dst, int* __restrict__ counts, int E) {
  int e = blockIdx.x * 256 + threadIdx.x;
  if (e < E) atomicAdd(&counts[dst[e]], 1);
}

__global__ void scan1_kernel(const int* __restrict__ counts, int* __restrict__ offs,
                             int* __restrict__ bsums, int n) {
  __shared__ int sd[1024];
  int t = threadIdx.x;
  int i = blockIdx.x * 1024 + t;
  int v = (i < n) ? counts[i] : 0;
  sd[t] = v;
  __syncthreads();
  for (int o = 1; o < 1024; o <<= 1) {
    int add = (t >= o) ? sd[t - o] : 0;
    __syncthreads();
    sd[t] += add;
    __syncthreads();
  }
  if (i < n) offs[i] = sd[t] - v;          // block-local exclusive
  if (t == 1023) bsums[blockIdx.x] = sd[1023];
}

__global__ void scan2_kernel(int* bsums, int nb) {
  if (threadIdx.x == 0 && blockIdx.x == 0) {
    int acc = 0;
    for (int i = 0; i < nb; i++) { int v = bsums[i]; bsums[i] = acc; acc += v; }
  }
}

__global__ void scan3_kernel(int* __restrict__ offs, const int* __restrict__ bsums,
                             int* __restrict__ cursor, int n, int E) {
  int i = blockIdx.x * 256 + threadIdx.x;
  if (i < n) {
    int v = offs[i] + bsums[i >> 10];
    offs[i] = v;
    cursor[i] = v;
  } else if (i == n) {
    offs[n] = E;
  }
}

// scatter precomputes, per edge, the PWL interval index for all 5 layers
// (same float compare as the original ballot, same stored rl, same unsorted
// kinks) packed 5x6 bits into epkS[].y; .x = src node.

__global__ void scatter_kernel(const float* __restrict__ pos, const int* __restrict__ src,
                               const int* __restrict__ dst, int* __restrict__ cursor,
                               const float* __restrict__ tksAll,
                               int2* __restrict__ epkS, float4* __restrict__ egeoS, int E) {
  __shared__ float sT[5 * HRAD];
  int t = threadIdx.x;
  if (t < 5 * HRAD) sT[t] = tksAll[t];
  __syncthreads();
  int e = blockIdx.x * 256 + t;
  if (e >= E) return;
  int s = src[e], d = dst[e];
  float rx = pos[d * 3 + 0] - pos[s * 3 + 0];
  float ry = pos[d * 3 + 1] - pos[s * 3 + 1];
  float rz = pos[d * 3 + 2] - pos[s * 3 + 2];
  float rl = sqrtf(rx * rx + ry * ry + rz * rz);
  float inv = 1.0f / (rl + 1e-6f);
  int ivpk = 0;
#pragma unroll
  for (int l = 0; l < 5; l++) {
    int cnt = 0;
#pragma unroll
    for (int k = 0; k < HRAD; k++) cnt += (rl > sT[l * HRAD + k]) ? 1 : 0;
    ivpk |= cnt << (6 * l);
  }
  int p = atomicAdd(&cursor[d], 1);
  epkS[p] = make_int2(s, ivpk);
  egeoS[p] = make_float4(rx * inv, ry * inv, rz * inv, rl);
}

// ---------------- degree-balanced schedule, contention-free build ----------------

__global__ void deghistA_kernel(const int* __restrict__ counts, int* __restrict__ bbase,
                                int n, int cpb) {
  __shared__ int lh[256];
  int t = threadIdx.x;
  lh[t] = 0;
  __syncthreads();
  int s = blockIdx.x * cpb, e = s + cpb; if (e > n) e = n;
  for (int i = s + t; i < e; i += 256) {
    int d = counts[i]; d = d > 255 ? 255 : d;
    atomicAdd(&lh[d], 1);
  }
  __syncthreads();
  bbase[blockIdx.x * 256 + t] = lh[t];
}

__global__ void degscanB_kernel(int* __restrict__ bbase) {
  __shared__ int sM[DG1 * 256];   // 48 KB
  __shared__ int gb[256];
  int t = threadIdx.x;            // 256 threads
  for (int i = t; i < DG1 * 256; i += 256) sM[i] = bbase[i];
  __syncthreads();
  int tot = 0;
  for (int b = 0; b < DG1; b++) tot += sM[b * 256 + t];
  gb[t] = tot;
  __syncthreads();
  if (t == 0) {                   // descending-degree exclusive scan
    int acc = 0;
    for (int d = 255; d >= 0; --d) { int v = gb[d]; gb[d] = acc; acc += v; }
  }
  __syncthreads();
  int run = gb[t];
  for (int b = 0; b < DG1; b++) { int v = sM[b * 256 + t]; sM[b * 256 + t] = run; run += v; }
  __syncthreads();
  for (int i = t; i < DG1 * 256; i += 256) bbase[i] = sM[i];
}

__global__ void degscatC_kernel(const int* __restrict__ counts, const int* __restrict__ bbase,
                                int* __restrict__ perm, int n, int cpb) {
  __shared__ int lc[256];
  int t = threadIdx.x;
  lc[t] = bbase[blockIdx.x * 256 + t];
  __syncthreads();
  int s = blockIdx.x * cpb, e = s + cpb; if (e > n) e = n;
  for (int i = s + t; i < e; i += 256) {
    int d = counts[i]; d = d > 255 ? 255 : d;
    int p = atomicAdd(&lc[d], 1);
    perm[p] = i;
  }
}

// ---------------- exact piecewise-linear collapse of the radial MLP ----------------

__global__ void pwl_build_kernel(const float* __restrict__ W1, const float* __restrict__ b1,
                                 const float* __restrict__ W2, const float* __restrict__ b2,
                                 float2* __restrict__ coef, float* __restrict__ tks) {
  int l = blockIdx.x / NIV;
  int iv = blockIdx.x - l * NIV;
  int tid = threadIdx.x;
  const float* w1 = W1 + l * HRAD;
  const float* bb1 = b1 + l * HRAD;
  const float* w2 = W2 + l * HRAD * NCH;
  const float* bb2 = b2 + l * NCH;
  __shared__ float a_s[HRAD], b_s[HRAD], t_s[HRAD], t_sorted[HRAD];
  if (tid < HRAD) {
    float a = w1[tid], b = bb1[tid];
    a_s[tid] = a; b_s[tid] = b;
    t_s[tid] = (a != 0.0f) ? (-b / a) : 1e30f;
  }
  __syncthreads();
  if (tid < HRAD) {
    float tj = t_s[tid];
    int rank = 0;
    for (int k = 0; k < HRAD; k++) {
      float tk = t_s[k];
      rank += (tk < tj) || (tk == tj && k < tid);
    }
    t_sorted[rank] = tj;
    if (iv == 0) tks[l * HRAD + tid] = tj;   // UNSORTED kinks (count-of-smaller is order-free)
  }
  __syncthreads();
  if (tid < NCH) {
    int k = tid;
    double lo = (iv == 0) ? (double)t_sorted[0] - 1.0 : (double)t_sorted[iv - 1];
    double hi = (iv == NIV - 1) ? (double)t_sorted[HRAD - 1] + 1.0 : (double)t_sorted[iv];
    double rm = 0.5 * (lo + hi);
    if (iv == 0) rm = (double)t_sorted[0] - 1.0;
    if (iv == NIV - 1) rm = (double)t_sorted[HRAD - 1] + 1.0;
    float alpha = bb2[k];
    float beta = 0.0f;
    for (int j = 0; j < HRAD; j++) {
      if ((double)a_s[j] * rm + (double)b_s[j] > 0.0) {
        float w = w2[j * NCH + k];
        alpha = fmaf(w, b_s[j], alpha);
        beta = fmaf(w, a_s[j], beta);
      }
    }
    // interleaved layout: [iv][c][path]
    coef[l * (NIV * NCH) + iv * NCH + (k & 31) * 7 + (k >> 5)] = make_float2(alpha, beta);
  }
}

// ---------------- initial pack (f0,f1 -> float4 rows) + q for layer 0 ----------------

__global__ __launch_bounds__(512) void pack_kernel(
    const float* __restrict__ f0, const float* __restrict__ f1,
    const float* __restrict__ Wq0, float scale0,
    float4* __restrict__ fpk, float* __restrict__ qbuf, int n) {
  __shared__ float sWq[1024];
  __shared__ float sF0[ET * 32];
  int tid = threadIdx.x;
  for (int i = tid; i < 1024; i += 512) sWq[i] = Wq0[i];
  __syncthreads();
  int nl = tid >> 5, c = tid & 31;
  for (int base = blockIdx.x * ET; base < n; base += gridDim.x * ET) {
    int node = base + nl;
    float v0 = 0.f, x = 0.f, y = 0.f, z = 0.f;
    if (node < n) {
      v0 = f0[(size_t)node * 32 + c];
      size_t b = ((size_t)node * 32 + c) * 3;
      x = f1[b]; y = f1[b + 1]; z = f1[b + 2];
      fpk[(size_t)node * 32 + c] = make_float4(v0, x, y, z);
    }
    sF0[nl * 32 + c] = v0;
    __syncthreads();
    if (node < n) {
      float q = 0.f;
#pragma unroll
      for (int k = 0; k < 32; k++) q = fmaf(sF0[nl * 32 + k], sWq[k * 32 + c], q);
      qbuf[(size_t)node * 32 + c] = q * scale0;
    }
    __syncthreads();
  }
}

// ---------------- per-node attention (softmax-weighted aggregation only) ----------------
// R7 kernel was latency-floored: F-gather had 1 iteration (~100 cy) of slack vs
// ~200-500 cy L2/L3 latency. This round: DEPTH-2 F pipeline. Records are
// prefetched to j+4 so the F-load for edge j+4 issues during iteration j ->
// 2 iterations of slack. Arithmetic is bit-identical to R7 (absmax sits at the
// 2^-10 threshold; only scheduling/register structure changed).

template<int CTRL>
__device__ __forceinline__ float dpp_xor_add(float t) {
  return t + __int_as_float(__builtin_amdgcn_update_dpp(
      0, __float_as_int(t), CTRL, 0xF, 0xF, true));
}

template<int CH>
__global__ __launch_bounds__(1024) void node_kernel(
    const float4* __restrict__ fpk, const float* __restrict__ qbuf,
    float4* __restrict__ Opk,
    const int2* __restrict__ epkS, const float4* __restrict__ egeoS,
    const int* __restrict__ offs, const int* __restrict__ perm,
    const float2* __restrict__ coefG, int ivshift,
    int n) {
  __shared__ float2 sCoef[NIV * NCH];   // 59136 B
  int tid = threadIdx.x;
  for (int i = tid; i < NIV * NCH; i += 1024) sCoef[i] = coefG[i];
  __syncthreads();

  int lane = tid & 63;
  int wid = tid >> 6;
  int c = lane & 31;
  int half = lane >> 5;

  int W = gridDim.x * 16;
  int gw = blockIdx.x * 16 + wid;

  // serpentine positions for strata 0,1,2
  int pos0 = gw;
  int pos1 = 2 * W - 1 - gw;
  int pos2 = 2 * W + gw;
  int kk = 2;                       // stratum of pos2

  // ---- wave preamble: perm 2-deep, first node's metadata + first edge record ----
  int pcur = (pos0 < n) ? perm[pos0] : 0;
  int pnext = (pos1 < n) ? perm[pos1] : 0;
  int start = 0, end = 0;
  float qs = 0.f;
  int2 pe = make_int2(0, 0);
  float4 pg = make_float4(0, 0, 0, 0);
  if (pos0 < n) {
    start = offs[pcur];
    end = offs[pcur + 1];
    qs = qbuf[pcur * 32 + c];
    int j0 = start + half;
    if (j0 < end) { pe = epkS[j0]; pg = egeoS[j0]; }
  }

  for (; pos0 < n; ) {
    // ---- prefetch perm 2 ahead + NEXT node's metadata (hidden under edge loop) ----
    int pnn = (pos2 < n) ? perm[pos2] : 0;
    int nstart = 0, nend = 0;
    float nqs = 0.f;
    if (pos1 < n) {
      nstart = offs[pnext];
      nend = offs[pnext + 1];
      nqs = qbuf[pnext * 32 + c];
    }

    float z = 0.0f;
    float o0 = 0.0f, o10 = 0.0f, o11 = 0.0f, o12 = 0.0f;

    int j = start + half;

    // ---- stage pipeline ----
    // cur  = edge j      : g_cur, F_cur, R_cur (ready)
    // next = edge j+2    : e_nx/g_nx record, F_nx load in flight; R folded per-iter
    // far  = edge j+4    : e_f2/g_f2 record
    float4 g_cur = pg;
    float4 F_cur = make_float4(0, 0, 0, 0);
    float R0 = 0, R1 = 0, R2 = 0, R3 = 0, R4 = 0, R5 = 0, R6 = 0;
    if (j < end) {
      F_cur = fpk[pe.x * 32 + c];
      int iv = (pe.y >> ivshift) & 63;
      const float2* cf = sCoef + (iv * 32 + c) * 7;
      float r = g_cur.w;
      R0 = fmaf(cf[0].y, r, cf[0].x);
      R1 = fmaf(cf[1].y, r, cf[1].x);
      R2 = fmaf(cf[2].y, r, cf[2].x);
      R3 = fmaf(cf[3].y, r, cf[3].x);
      R4 = fmaf(cf[4].y, r, cf[4].x);
      R5 = fmaf(cf[5].y, r, cf[5].x);
      R6 = fmaf(cf[6].y, r, cf[6].x);
    }
    int2 e_nx = make_int2(0, 0);
    float4 g_nx = make_float4(0, 0, 0, 0);
    if (j + 2 < end) { e_nx = epkS[j + 2]; g_nx = egeoS[j + 2]; }
    int2 e_f2 = make_int2(0, 0);
    float4 g_f2 = make_float4(0, 0, 0, 0);
    if (j + 4 < end) { e_f2 = epkS[j + 4]; g_f2 = egeoS[j + 4]; }
    float4 F_nx = make_float4(0, 0, 0, 0);
    if (j + 2 < end) F_nx = fpk[e_nx.x * 32 + c];

    while (j < end) {
      int j2 = j + 2;
      // ---- issue F for edge j+4 (consumed 2 iterations later) ----
      float4 Fb = make_float4(0, 0, 0, 0);
      if (j + 4 < end) Fb = fpk[e_f2.x * 32 + c];
      // ---- record for edge j+6 ----
      int2 e3 = make_int2(0, 0);
      float4 g3 = make_float4(0, 0, 0, 0);
      if (j + 6 < end) { e3 = epkS[j + 6]; g3 = egeoS[j + 6]; }
      // ---- R-fold for edge j+2 (LDS; consumed next iteration) ----
      float N0 = 0, N1 = 0, N2 = 0, N3 = 0, N4 = 0, N5 = 0, N6 = 0;
      {
        int iv = (e_nx.y >> ivshift) & 63;
        const float2* cf = sCoef + (iv * 32 + c) * 7;
        float r = g_nx.w;
        N0 = fmaf(cf[0].y, r, cf[0].x);
        N1 = fmaf(cf[1].y, r, cf[1].x);
        N2 = fmaf(cf[2].y, r, cf[2].x);
        N3 = fmaf(cf[3].y, r, cf[3].x);
        N4 = fmaf(cf[4].y, r, cf[4].x);
        N5 = fmaf(cf[5].y, r, cf[5].x);
        N6 = fmaf(cf[6].y, r, cf[6].x);
      }

      // ---- body: edge j (all operands ready) ----
      float dot1 = fmaf(F_cur.y, g_cur.x, fmaf(F_cur.z, g_cur.y, F_cur.w * g_cur.z));
      float t = qs * fmaf(R0, F_cur.x, R1 * dot1);
      t = dpp_xor_add<0xB1>(t);    // quad_perm(1,0,3,2)
      t = dpp_xor_add<0x4E>(t);    // quad_perm(2,3,0,1)
      t = dpp_xor_add<0x141>(t);   // row_half_mirror == xor4 (quads uniform)
      if constexpr (CH == 32) {
        t = dpp_xor_add<0x140>(t); // row_mirror == xor8 (8-groups uniform)
        t = t + __int_as_float(__builtin_amdgcn_ds_swizzle(
                __float_as_int(t), 0x401F));   // xor16 within 32-lane half
      }
      float p = __builtin_amdgcn_exp2f(t);
      z += p;
      float v0 = fmaf(R2, F_cur.x, R3 * dot1);
      float sg = fmaf(R5, F_cur.x, R6 * dot1);
      o0  = fmaf(p, v0, o0);
      o10 = fmaf(p, fmaf(R4, F_cur.y, sg * g_cur.x), o10);
      o11 = fmaf(p, fmaf(R4, F_cur.z, sg * g_cur.y), o11);
      o12 = fmaf(p, fmaf(R4, F_cur.w, sg * g_cur.z), o12);

      // ---- rotate pipeline ----
      g_cur = g_nx; F_cur = F_nx;
      R0 = N0; R1 = N1; R2 = N2; R3 = N3; R4 = N4; R5 = N5; R6 = N6;
      e_nx = e_f2; g_nx = g_f2; F_nx = Fb;
      e_f2 = e3; g_f2 = g3;
      j = j2;
    }

    // ---- prefetch NEXT node's first edge record (nstart arrived long ago) ----
    pe = make_int2(0, 0);
    pg = make_float4(0, 0, 0, 0);
    if (pos1 < n) {
      int nj = nstart + half;
      if (nj < nend) { pe = epkS[nj]; pg = egeoS[nj]; }
    }

    // ---- merge the two half-wave states (plain sums) ----
    float zo  = __shfl_xor(z, 32, 64);
    float p0  = __shfl_xor(o0, 32, 64);
    float p10 = __shfl_xor(o10, 32, 64);
    float p11 = __shfl_xor(o11, 32, 64);
    float p12 = __shfl_xor(o12, 32, 64);
    float zf = z + zo;
    float inv = 1.0f / (zf + 1e-6f);
    if (!half) {
      Opk[pcur * 32 + c] = make_float4(
          (o0 + p0) * inv,
          (o10 + p10) * inv,
          (o11 + p11) * inv,
          (o12 + p12) * inv);
    }

    // ---- rotate node pipeline state (serpentine position step) ----
    pcur = pnext;
    pnext = pnn;
    start = nstart;
    end = nend;
    qs = nqs;
    pos0 = pos1;
    pos1 = pos2;
    ++kk;
    pos2 = kk * W + ((kk & 1) ? (W - 1 - gw) : gw);
  }
}

// ---------------- dense epilogue: out = O@Wo + f@Ws, NL, next-layer q ----------------

__global__ __launch_bounds__(512) void epi_kernel(
    const float4* __restrict__ Opk, float4* __restrict__ fpk,
    const float* __restrict__ Wo0G, const float* __restrict__ Ws0G,
    const float* __restrict__ Wo1G, const float* __restrict__ Ws1G,
    const float* __restrict__ bgG,
    const float* __restrict__ WqN, float* __restrict__ qbuf, float scaleN,
    float* __restrict__ out0, float* __restrict__ out1,
    int mode, int n) {
  __shared__ float4 sW[32 * 32];     // (wo0, ws0, wo1, ws1) 16 KB
  __shared__ float  sWq[32 * 32];    // 4 KB
  __shared__ float4 sO[ET * 32];     // 8 KB
  __shared__ float4 sF[ET * 32];     // 8 KB
  __shared__ float  sF0[ET * 32];    // 2 KB
  int tid = threadIdx.x;
  for (int i = tid; i < 1024; i += 512) {
    sW[i] = make_float4(Wo0G[i], Ws0G[i], Wo1G[i], Ws1G[i]);
    if (mode == 0) sWq[i] = WqN[i];
  }
  __syncthreads();
  int nl = tid >> 5;
  int c  = tid & 31;
  for (int base = blockIdx.x * ET; base < n; base += gridDim.x * ET) {
    int node = base + nl;
    bool valid = node < n;
    if (valid) {
      sO[tid] = Opk[(size_t)node * 32 + c];
      sF[tid] = fpk[(size_t)node * 32 + c];
    }
    __syncthreads();
    float a0 = 0.f, ax = 0.f, ay = 0.f, az = 0.f;
#pragma unroll
    for (int k = 0; k < 32; k++) {
      float4 O = sO[nl * 32 + k];
      float4 F = sF[nl * 32 + k];
      float4 w = sW[k * 32 + c];
      a0 = fmaf(O.x, w.x, fmaf(F.x, w.y, a0));
      ax = fmaf(O.y, w.z, fmaf(F.y, w.w, ax));
      ay = fmaf(O.z, w.z, fmaf(F.z, w.w, ay));
      az = fmaf(O.w, w.z, fmaf(F.w, w.w, az));
    }
    if (mode == 0) {
      float f0n = fmaxf(a0, 0.f);
      float n1 = sqrtf(fmaf(ax, ax, fmaf(ay, ay, az * az)));
      float gate = fmaxf(n1 + bgG[c], 0.f) / (n1 + 1e-6f);
      if (valid) fpk[(size_t)node * 32 + c] = make_float4(f0n, ax * gate, ay * gate, az * gate);
      sF0[nl * 32 + c] = f0n;
      __syncthreads();
      if (valid) {
        float q = 0.f;
#pragma unroll
        for (int k = 0; k < 32; k++) q = fmaf(sF0[nl * 32 + k], sWq[k * 32 + c], q);
        qbuf[(size_t)node * 32 + c] = q * scaleN;
      }
      __syncthreads();
    } else {
      if (valid) {
        out0[(size_t)node * 32 + c] = a0;
        size_t b = ((size_t)node * 32 + c) * 3;
        out1[b] = ax; out1[b + 1] = ay; out1[b + 2] = az;
      }
      __syncthreads();
    }
  }
}

// ---------------- host launch ----------------

extern "C" void kernel_launch(void* const* d_in, const int* in_sizes, int n_in,
                              void* d_out, int out_size, void* d_ws, size_t ws_size,
                              hipStream_t stream) {
  const float* pos = (const float*)d_in[0];
  const float* f0  = (const float*)d_in[1];
  const float* f1  = (const float*)d_in[2];
  const int* src   = (const int*)d_in[3];
  const int* dst   = (const int*)d_in[4];
  const float* W1  = (const float*)d_in[5];
  const float* b1  = (const float*)d_in[6];
  const float* W2  = (const float*)d_in[7];
  const float* b2  = (const float*)d_in[8];
  const float* Wq  = (const float*)d_in[9];
  const float* Wo0 = (const float*)d_in[10];
  const float* Wo1 = (const float*)d_in[11];
  const float* Ws0 = (const float*)d_in[12];
  const float* Ws1 = (const float*)d_in[13];
  const float* bg  = (const float*)d_in[14];

  int N = in_sizes[0] / 3;
  int E = in_sizes[3];

  char* p = (char*)d_ws;
  auto alloc = [&](size_t bytes) {
    char* r = p;
    p += (bytes + 255) & ~(size_t)255;
    return r;
  };
  int* counts   = (int*)alloc((size_t)N * 4);
  int* offs     = (int*)alloc((size_t)(N + 1) * 4);
  int* cursor   = (int*)alloc((size_t)N * 4);
  int* bsums    = (int*)alloc(1024 * 4);
  int2* epkS    = (int2*)alloc((size_t)E * 8);
  float4* egeoS = (float4*)alloc((size_t)E * 16);
  float2* coef  = (float2*)alloc((size_t)5 * NIV * NCH * 8);
  float* tks    = (float*)alloc((size_t)5 * HRAD * 4);
  float4* fpk   = (float4*)alloc((size_t)N * CCH * 16);
  float4* Opk   = (float4*)alloc((size_t)N * CCH * 16);
  float* qbuf   = (float*)alloc((size_t)N * CCH * 4);
  int* bbase    = (int*)alloc((size_t)DG1 * 256 * 4);
  int* perm     = (int*)alloc((size_t)N * 4);

  int cpb = (N + DG1 - 1) / DG1;

  pwl_build_kernel<<<5 * NIV, 256, 0, stream>>>(W1, b1, W2, b2, coef, tks);
  hipMemsetAsync(counts, 0, (size_t)N * 4, stream);
  hist_kernel<<<(E + 255) / 256, 256, 0, stream>>>(dst, counts, E);
  deghistA_kernel<<<DG1, 256, 0, stream>>>(counts, bbase, N, cpb);
  int nb = (N + 1023) / 1024;
  scan1_kernel<<<nb, 1024, 0, stream>>>(counts, offs, bsums, N);
  scan2_kernel<<<1, 64, 0, stream>>>(bsums, nb);
  scan3_kernel<<<(N + 1 + 255) / 256, 256, 0, stream>>>(offs, bsums, cursor, N, E);
  degscanB_kernel<<<1, 256, 0, stream>>>(bbase);
  degscatC_kernel<<<DG1, 256, 0, stream>>>(counts, bbase, perm, N, cpb);
  scatter_kernel<<<(E + 255) / 256, 256, 0, stream>>>(pos, src, dst, cursor, tks,
                                                      epkS, egeoS, E);

  // log2(e) folded into the q pre-scale: softmax runs in exp2 domain.
  const float LOG2E = 1.4426950408889634f;
  float sc8 = LOG2E / sqrtf(8.0f);
  float sc32 = LOG2E / sqrtf(32.0f);
  int nblk = (N + ET - 1) / ET;
  pack_kernel<<<nblk, 512, 0, stream>>>(f0, f1, Wq, sc8, fpk, qbuf, N);

  float* out0 = (float*)d_out;
  float* out1 = out0 + (size_t)N * CCH;
  for (int l = 0; l < 5; l++) {
    bool last = (l == 4);
    if (last) {
      node_kernel<32><<<512, 1024, 0, stream>>>(
          fpk, qbuf, Opk, epkS, egeoS, offs, perm,
          coef + (size_t)l * NIV * NCH, 6 * l, N);
    } else {
      node_kernel<8><<<512, 1024, 0, stream>>>(
          fpk, qbuf, Opk, epkS, egeoS, offs, perm,
          coef + (size_t)l * NIV * NCH, 6 * l, N);
    }
    epi_kernel<<<nblk, 512, 0, stream>>>(
        Opk, fpk,
        Wo0 + l * CCH * CCH, Ws0 + l * CCH * CCH,
        Wo1 + l * CCH * CCH, Ws1 + l * CCH * CCH,
        bg + (last ? 0 : l) * CCH,
        Wq + (l + 1 <= 4 ? (l + 1) : 4) * CCH * CCH, qbuf,
        (l + 1 == 4) ? sc32 : sc8,
        out0, out1, last ? 1 : 0, N);
  }
}

// Round 9
// 814.931 us; speedup vs baseline: 1.0211x; 1.0211x over previous
//
#include <hip/hip_runtime.h>
#include <math.h>

#define CCH 32        // channels
#define NCH 224       // 7*C radial outputs
#define NIV 33        // PWL intervals
#define HRAD 32
#define ET 16         // nodes per epi block-iter
#define DG1 48        // blocks for degree counting sort (LDS-privatized)

// ---------------- CSR build ----------------

__global__ void hist_kernel(const int* __restrict__ dst, int* __restrict__ counts, int E) {
  int e = blockIdx.x * 256 + threadIdx.x;
  if (e < E) atomicAdd(&counts[dst[e]], 1);
}

__global__ void scan1_kernel(const int* __restrict__ counts, int* __restrict__ offs,
                             int* __restrict__ bsums, int n) {
  __shared__ int sd[1024];
  int t = threadIdx.x;
  int i = blockIdx.x * 1024 + t;
  int v = (i < n) ? counts[i] : 0;
  sd[t] = v;
  __syncthreads();
  for (int o = 1; o < 1024; o <<= 1) {
    int add = (t >= o) ? sd[t - o] : 0;
    __syncthreads();
    sd[t] += add;
    __syncthreads();
  }
  if (i < n) offs[i] = sd[t] - v;          // block-local exclusive
  if (t == 1023) bsums[blockIdx.x] = sd[1023];
}

__global__ void scan2_kernel(int* bsums, int nb) {
  if (threadIdx.x == 0 && blockIdx.x == 0) {
    int acc = 0;
    for (int i = 0; i < nb; i++) { int v = bsums[i]; bsums[i] = acc; acc += v; }
  }
}

__global__ void scan3_kernel(int* __restrict__ offs, const int* __restrict__ bsums,
                             int* __restrict__ cursor, int n, int E) {
  int i = blockIdx.x * 256 + threadIdx.x;
  if (i < n) {
    int v = offs[i] + bsums[i >> 10];
    offs[i] = v;
    cursor[i] = v;
  } else if (i == n) {
    offs[n] = E;
  }
}

// scatter precomputes, per edge, the PWL interval index for all 5 layers
// (same float compare as the original ballot, same stored rl, same unsorted
// kinks) packed 5x6 bits into epkS[].y; .x = src node.

__global__ void scatter_kernel(const float* __restrict__ pos, const int* __restrict__ src,
                               const int* __restrict__ dst, int* __restrict__ cursor,
                               const float* __restrict__ tksAll,
                               int2* __restrict__ epkS, float4* __restrict__ egeoS, int E) {
  __shared__ float sT[5 * HRAD];
  int t = threadIdx.x;
  if (t < 5 * HRAD) sT[t] = tksAll[t];
  __syncthreads();
  int e = blockIdx.x * 256 + t;
  if (e >= E) return;
  int s = src[e], d = dst[e];
  float rx = pos[d * 3 + 0] - pos[s * 3 + 0];
  float ry = pos[d * 3 + 1] - pos[s * 3 + 1];
  float rz = pos[d * 3 + 2] - pos[s * 3 + 2];
  float rl = sqrtf(rx * rx + ry * ry + rz * rz);
  float inv = 1.0f / (rl + 1e-6f);
  int ivpk = 0;
#pragma unroll
  for (int l = 0; l < 5; l++) {
    int cnt = 0;
#pragma unroll
    for (int k = 0; k < HRAD; k++) cnt += (rl > sT[l * HRAD + k]) ? 1 : 0;
    ivpk |= cnt << (6 * l);
  }
  int p = atomicAdd(&cursor[d], 1);
  epkS[p] = make_int2(s, ivpk);
  egeoS[p] = make_float4(rx * inv, ry * inv, rz * inv, rl);
}

// ---------------- degree-balanced schedule, contention-free build ----------------

__global__ void deghistA_kernel(const int* __restrict__ counts, int* __restrict__ bbase,
                                int n, int cpb) {
  __shared__ int lh[256];
  int t = threadIdx.x;
  lh[t] = 0;
  __syncthreads();
  int s = blockIdx.x * cpb, e = s + cpb; if (e > n) e = n;
  for (int i = s + t; i < e; i += 256) {
    int d = counts[i]; d = d > 255 ? 255 : d;
    atomicAdd(&lh[d], 1);
  }
  __syncthreads();
  bbase[blockIdx.x * 256 + t] = lh[t];
}

__global__ void degscanB_kernel(int* __restrict__ bbase) {
  __shared__ int sM[DG1 * 256];   // 48 KB
  __shared__ int gb[256];
  int t = threadIdx.x;            // 256 threads
  for (int i = t; i < DG1 * 256; i += 256) sM[i] = bbase[i];
  __syncthreads();
  int tot = 0;
  for (int b = 0; b < DG1; b++) tot += sM[b * 256 + t];
  gb[t] = tot;
  __syncthreads();
  if (t == 0) {                   // descending-degree exclusive scan
    int acc = 0;
    for (int d = 255; d >= 0; --d) { int v = gb[d]; gb[d] = acc; acc += v; }
  }
  __syncthreads();
  int run = gb[t];
  for (int b = 0; b < DG1; b++) { int v = sM[b * 256 + t]; sM[b * 256 + t] = run; run += v; }
  __syncthreads();
  for (int i = t; i < DG1 * 256; i += 256) bbase[i] = sM[i];
}

__global__ void degscatC_kernel(const int* __restrict__ counts, const int* __restrict__ bbase,
                                int* __restrict__ perm, int n, int cpb) {
  __shared__ int lc[256];
  int t = threadIdx.x;
  lc[t] = bbase[blockIdx.x * 256 + t];
  __syncthreads();
  int s = blockIdx.x * cpb, e = s + cpb; if (e > n) e = n;
  for (int i = s + t; i < e; i += 256) {
    int d = counts[i]; d = d > 255 ? 255 : d;
    int p = atomicAdd(&lc[d], 1);
    perm[p] = i;
  }
}

// ---------------- exact piecewise-linear collapse of the radial MLP ----------------

__global__ void pwl_build_kernel(const float* __restrict__ W1, const float* __restrict__ b1,
                                 const float* __restrict__ W2, const float* __restrict__ b2,
                                 float2* __restrict__ coef, float* __restrict__ tks) {
  int l = blockIdx.x / NIV;
  int iv = blockIdx.x - l * NIV;
  int tid = threadIdx.x;
  const float* w1 = W1 + l * HRAD;
  const float* bb1 = b1 + l * HRAD;
  const float* w2 = W2 + l * HRAD * NCH;
  const float* bb2 = b2 + l * NCH;
  __shared__ float a_s[HRAD], b_s[HRAD], t_s[HRAD], t_sorted[HRAD];
  if (tid < HRAD) {
    float a = w1[tid], b = bb1[tid];
    a_s[tid] = a; b_s[tid] = b;
    t_s[tid] = (a != 0.0f) ? (-b / a) : 1e30f;
  }
  __syncthreads();
  if (tid < HRAD) {
    float tj = t_s[tid];
    int rank = 0;
    for (int k = 0; k < HRAD; k++) {
      float tk = t_s[k];
      rank += (tk < tj) || (tk == tj && k < tid);
    }
    t_sorted[rank] = tj;
    if (iv == 0) tks[l * HRAD + tid] = tj;   // UNSORTED kinks (count-of-smaller is order-free)
  }
  __syncthreads();
  if (tid < NCH) {
    int k = tid;
    double lo = (iv == 0) ? (double)t_sorted[0] - 1.0 : (double)t_sorted[iv - 1];
    double hi = (iv == NIV - 1) ? (double)t_sorted[HRAD - 1] + 1.0 : (double)t_sorted[iv];
    double rm = 0.5 * (lo + hi);
    if (iv == 0) rm = (double)t_sorted[0] - 1.0;
    if (iv == NIV - 1) rm = (double)t_sorted[HRAD - 1] + 1.0;
    float alpha = bb2[k];
    float beta = 0.0f;
    for (int j = 0; j < HRAD; j++) {
      if ((double)a_s[j] * rm + (double)b_s[j] > 0.0) {
        float w = w2[j * NCH + k];
        alpha = fmaf(w, b_s[j], alpha);
        beta = fmaf(w, a_s[j], beta);
      }
    }
    // interleaved layout: [iv][c][path]
    coef[l * (NIV * NCH) + iv * NCH + (k & 31) * 7 + (k >> 5)] = make_float2(alpha, beta);
  }
}

// ---------------- initial pack (f0,f1 -> float4 rows) + q for layer 0 ----------------

__global__ __launch_bounds__(512) void pack_kernel(
    const float* __restrict__ f0, const float* __restrict__ f1,
    const float* __restrict__ Wq0, float scale0,
    float4* __restrict__ fpk, float* __restrict__ qbuf, int n) {
  __shared__ float sWq[1024];
  __shared__ float sF0[ET * 32];
  int tid = threadIdx.x;
  for (int i = tid; i < 1024; i += 512) sWq[i] = Wq0[i];
  __syncthreads();
  int nl = tid >> 5, c = tid & 31;
  for (int base = blockIdx.x * ET; base < n; base += gridDim.x * ET) {
    int node = base + nl;
    float v0 = 0.f, x = 0.f, y = 0.f, z = 0.f;
    if (node < n) {
      v0 = f0[(size_t)node * 32 + c];
      size_t b = ((size_t)node * 32 + c) * 3;
      x = f1[b]; y = f1[b + 1]; z = f1[b + 2];
      fpk[(size_t)node * 32 + c] = make_float4(v0, x, y, z);
    }
    sF0[nl * 32 + c] = v0;
    __syncthreads();
    if (node < n) {
      float q = 0.f;
#pragma unroll
      for (int k = 0; k < 32; k++) q = fmaf(sF0[nl * 32 + k], sWq[k * 32 + c], q);
      qbuf[(size_t)node * 32 + c] = q * scale0;
    }
    __syncthreads();
  }
}

// ---------------- per-node attention (softmax-weighted aggregation only) ----------------
// R8 lesson: runtime register rotation of in-flight loads forces the waitcnt at
// the mov, collapsing the pipeline. This round: period-2 unrolled edge loop
// (P/Q bodies, STATIC register names). Each body consumes F issued ~1.3-1.5
// bodies earlier in the SAME register, then re-issues into it (WAR, no mov).
// Records are CSR-sequential (L1/L2-line-resident) -> staged one trip ahead.
// R-fold one body ahead. Accumulation order (j, j+2, j+4...) bit-identical.
// Serpentine balance, no-max exp2 softmax, DPP reduce, 32-bit idx all kept.

template<int CTRL>
__device__ __forceinline__ float dpp_xor_add(float t) {
  return t + __int_as_float(__builtin_amdgcn_update_dpp(
      0, __float_as_int(t), CTRL, 0xF, 0xF, true));
}

#define RFOLD(D0,D1,D2,D3,D4,D5,D6, IVV, GW)                      \
  {                                                                \
    const float2* cf_ = sCoef + ((IVV) * 32 + c) * 7;              \
    float r_ = (GW);                                               \
    D0 = fmaf(cf_[0].y, r_, cf_[0].x);                             \
    D1 = fmaf(cf_[1].y, r_, cf_[1].x);                             \
    D2 = fmaf(cf_[2].y, r_, cf_[2].x);                             \
    D3 = fmaf(cf_[3].y, r_, cf_[3].x);                             \
    D4 = fmaf(cf_[4].y, r_, cf_[4].x);                             \
    D5 = fmaf(cf_[5].y, r_, cf_[5].x);                             \
    D6 = fmaf(cf_[6].y, r_, cf_[6].x);                             \
  }

#define EBODY(FF, GG, R0_,R1_,R2_,R3_,R4_,R5_,R6_)                                   \
  {                                                                                   \
    float dot1 = fmaf(FF.y, GG.x, fmaf(FF.z, GG.y, FF.w * GG.z));                     \
    float t = qs * fmaf(R0_, FF.x, R1_ * dot1);                                       \
    t = dpp_xor_add<0xB1>(t);                                                         \
    t = dpp_xor_add<0x4E>(t);                                                         \
    t = dpp_xor_add<0x141>(t);                                                        \
    if constexpr (CH == 32) {                                                         \
      t = dpp_xor_add<0x140>(t);                                                      \
      t = t + __int_as_float(__builtin_amdgcn_ds_swizzle(                             \
              __float_as_int(t), 0x401F));                                            \
    }                                                                                 \
    float p = __builtin_amdgcn_exp2f(t);                                              \
    z += p;                                                                           \
    float v0 = fmaf(R2_, FF.x, R3_ * dot1);                                           \
    float sg = fmaf(R5_, FF.x, R6_ * dot1);                                           \
    o0  = fmaf(p, v0, o0);                                                            \
    o10 = fmaf(p, fmaf(R4_, FF.y, sg * GG.x), o10);                                   \
    o11 = fmaf(p, fmaf(R4_, FF.z, sg * GG.y), o11);                                   \
    o12 = fmaf(p, fmaf(R4_, FF.w, sg * GG.z), o12);                                   \
  }

template<int CH>
__global__ __launch_bounds__(1024) void node_kernel(
    const float4* __restrict__ fpk, const float* __restrict__ qbuf,
    float4* __restrict__ Opk,
    const int2* __restrict__ epkS, const float4* __restrict__ egeoS,
    const int* __restrict__ offs, const int* __restrict__ perm,
    const float2* __restrict__ coefG, int ivshift,
    int n) {
  __shared__ float2 sCoef[NIV * NCH];   // 59136 B
  int tid = threadIdx.x;
  for (int i = tid; i < NIV * NCH; i += 1024) sCoef[i] = coefG[i];
  __syncthreads();

  int lane = tid & 63;
  int wid = tid >> 6;
  int c = lane & 31;
  int half = lane >> 5;

  int W = gridDim.x * 16;
  int gw = blockIdx.x * 16 + wid;

  // serpentine positions for strata 0,1,2
  int pos0 = gw;
  int pos1 = 2 * W - 1 - gw;
  int pos2 = 2 * W + gw;
  int kk = 2;                       // stratum of pos2

  // ---- wave preamble: perm 2-deep, first node's metadata + first edge record ----
  int pcur = (pos0 < n) ? perm[pos0] : 0;
  int pnext = (pos1 < n) ? perm[pos1] : 0;
  int start = 0, end = 0;
  float qs = 0.f;
  int2 pe = make_int2(0, 0);
  float4 pg = make_float4(0, 0, 0, 0);
  if (pos0 < n) {
    start = offs[pcur];
    end = offs[pcur + 1];
    qs = qbuf[pcur * 32 + c];
    int j0 = start + half;
    if (j0 < end) { pe = epkS[j0]; pg = egeoS[j0]; }
  }

  for (; pos0 < n; ) {
    // ---- prefetch perm 2 ahead + NEXT node's metadata (hidden under edge loop) ----
    int pnn = (pos2 < n) ? perm[pos2] : 0;
    int nstart = 0, nend = 0;
    float nqs = 0.f;
    if (pos1 < n) {
      nstart = offs[pnext];
      nend = offs[pnext + 1];
      nqs = qbuf[pnext * 32 + c];
    }

    float z = 0.0f;
    float o0 = 0.0f, o10 = 0.0f, o11 = 0.0f, o12 = 0.0f;

    int j = start + half;

    // ---- prologue: stage P=edge j, Q=edge j+2 ----
    float4 g_p = make_float4(0, 0, 0, 0), g_q = make_float4(0, 0, 0, 0);
    int iv_p = 0, iv_q = 0;
    float4 F_p = make_float4(0, 0, 0, 0), F_q = make_float4(0, 0, 0, 0);
    float P0 = 0, P1 = 0, P2 = 0, P3 = 0, P4 = 0, P5 = 0, P6 = 0;
    float Q0 = 0, Q1 = 0, Q2 = 0, Q3 = 0, Q4 = 0, Q5 = 0, Q6 = 0;
    if (j < end) {
      g_p = pg;
      iv_p = (pe.y >> ivshift) & 63;
      F_p = fpk[pe.x * 32 + c];
      RFOLD(P0, P1, P2, P3, P4, P5, P6, iv_p, g_p.w);
    }
    if (j + 2 < end) {
      int2 e1 = epkS[j + 2];
      float4 ge1 = egeoS[j + 2];
      g_q = ge1;
      iv_q = (e1.y >> ivshift) & 63;
      F_q = fpk[e1.x * 32 + c];
    }

    // ---- main trips: process edges j (P) and j+2 (Q); j advances by 4 ----
    while (j + 2 < end) {
      // stage records for j+4, j+6 (CSR-sequential -> L1/L2 line hits)
      int2 r4 = make_int2(0, 0);
      float4 gg4 = make_float4(0, 0, 0, 0);
      if (j + 4 < end) { r4 = epkS[j + 4]; gg4 = egeoS[j + 4]; }
      int2 r6 = make_int2(0, 0);
      float4 gg6 = make_float4(0, 0, 0, 0);
      if (j + 6 < end) { r6 = epkS[j + 6]; gg6 = egeoS[j + 6]; }

      // P: fold R for Q's edge (j+2), then consume P (edge j)
      RFOLD(Q0, Q1, Q2, Q3, Q4, Q5, Q6, iv_q, g_q.w);
      EBODY(F_p, g_p, P0, P1, P2, P3, P4, P5, P6);
      // advance P stage to edge j+4 (reuse same registers; no in-flight movs)
      g_p = gg4;
      iv_p = (r4.y >> ivshift) & 63;
      if (j + 4 < end) F_p = fpk[r4.x * 32 + c];

      // Q: fold R for next P edge (j+4), then consume Q (edge j+2)
      RFOLD(P0, P1, P2, P3, P4, P5, P6, iv_p, g_p.w);
      EBODY(F_q, g_q, Q0, Q1, Q2, Q3, Q4, Q5, Q6);
      // advance Q stage to edge j+6
      g_q = gg6;
      iv_q = (r6.y >> ivshift) & 63;
      if (j + 6 < end) F_q = fpk[r6.x * 32 + c];

      j += 4;
    }
    // ---- epilogue: at most one edge (j) remains; its F/g/R are staged in P ----
    if (j < end) {
      EBODY(F_p, g_p, P0, P1, P2, P3, P4, P5, P6);
    }

    // ---- prefetch NEXT node's first edge record (nstart arrived long ago) ----
    pe = make_int2(0, 0);
    pg = make_float4(0, 0, 0, 0);
    if (pos1 < n) {
      int nj = nstart + half;
      if (nj < nend) { pe = epkS[nj]; pg = egeoS[nj]; }
    }

    // ---- merge the two half-wave states (plain sums) ----
    float zo  = __shfl_xor(z, 32, 64);
    float p0  = __shfl_xor(o0, 32, 64);
    float p10 = __shfl_xor(o10, 32, 64);
    float p11 = __shfl_xor(o11, 32, 64);
    float p12 = __shfl_xor(o12, 32, 64);
    float zf = z + zo;
    float inv = 1.0f / (zf + 1e-6f);
    if (!half) {
      Opk[pcur * 32 + c] = make_float4(
          (o0 + p0) * inv,
          (o10 + p10) * inv,
          (o11 + p11) * inv,
          (o12 + p12) * inv);
    }

    // ---- rotate node pipeline state (serpentine position step) ----
    pcur = pnext;
    pnext = pnn;
    start = nstart;
    end = nend;
    qs = nqs;
    pos0 = pos1;
    pos1 = pos2;
    ++kk;
    pos2 = kk * W + ((kk & 1) ? (W - 1 - gw) : gw);
  }
}

// ---------------- dense epilogue: out = O@Wo + f@Ws, NL, next-layer q ----------------

__global__ __launch_bounds__(512) void epi_kernel(
    const float4* __restrict__ Opk, float4* __restrict__ fpk,
    const float* __restrict__ Wo0G, const float* __restrict__ Ws0G,
    const float* __restrict__ Wo1G, const float* __restrict__ Ws1G,
    const float* __restrict__ bgG,
    const float* __restrict__ WqN, float* __restrict__ qbuf, float scaleN,
    float* __restrict__ out0, float* __restrict__ out1,
    int mode, int n) {
  __shared__ float4 sW[32 * 32];     // (wo0, ws0, wo1, ws1) 16 KB
  __shared__ float  sWq[32 * 32];    // 4 KB
  __shared__ float4 sO[ET * 32];     // 8 KB
  __shared__ float4 sF[ET * 32];     // 8 KB
  __shared__ float  sF0[ET * 32];    // 2 KB
  int tid = threadIdx.x;
  for (int i = tid; i < 1024; i += 512) {
    sW[i] = make_float4(Wo0G[i], Ws0G[i], Wo1G[i], Ws1G[i]);
    if (mode == 0) sWq[i] = WqN[i];
  }
  __syncthreads();
  int nl = tid >> 5;
  int c  = tid & 31;
  for (int base = blockIdx.x * ET; base < n; base += gridDim.x * ET) {
    int node = base + nl;
    bool valid = node < n;
    if (valid) {
      sO[tid] = Opk[(size_t)node * 32 + c];
      sF[tid] = fpk[(size_t)node * 32 + c];
    }
    __syncthreads();
    float a0 = 0.f, ax = 0.f, ay = 0.f, az = 0.f;
#pragma unroll
    for (int k = 0; k < 32; k++) {
      float4 O = sO[nl * 32 + k];
      float4 F = sF[nl * 32 + k];
      float4 w = sW[k * 32 + c];
      a0 = fmaf(O.x, w.x, fmaf(F.x, w.y, a0));
      ax = fmaf(O.y, w.z, fmaf(F.y, w.w, ax));
      ay = fmaf(O.z, w.z, fmaf(F.z, w.w, ay));
      az = fmaf(O.w, w.z, fmaf(F.w, w.w, az));
    }
    if (mode == 0) {
      float f0n = fmaxf(a0, 0.f);
      float n1 = sqrtf(fmaf(ax, ax, fmaf(ay, ay, az * az)));
      float gate = fmaxf(n1 + bgG[c], 0.f) / (n1 + 1e-6f);
      if (valid) fpk[(size_t)node * 32 + c] = make_float4(f0n, ax * gate, ay * gate, az * gate);
      sF0[nl * 32 + c] = f0n;
      __syncthreads();
      if (valid) {
        float q = 0.f;
#pragma unroll
        for (int k = 0; k < 32; k++) q = fmaf(sF0[nl * 32 + k], sWq[k * 32 + c], q);
        qbuf[(size_t)node * 32 + c] = q * scaleN;
      }
      __syncthreads();
    } else {
      if (valid) {
        out0[(size_t)node * 32 + c] = a0;
        size_t b = ((size_t)node * 32 + c) * 3;
        out1[b] = ax; out1[b + 1] = ay; out1[b + 2] = az;
      }
      __syncthreads();
    }
  }
}

// ---------------- host launch ----------------

extern "C" void kernel_launch(void* const* d_in, const int* in_sizes, int n_in,
                              void* d_out, int out_size, void* d_ws, size_t ws_size,
                              hipStream_t stream) {
  const float* pos = (const float*)d_in[0];
  const float* f0  = (const float*)d_in[1];
  const float* f1  = (const float*)d_in[2];
  const int* src   = (const int*)d_in[3];
  const int* dst   = (const int*)d_in[4];
  const float* W1  = (const float*)d_in[5];
  const float* b1  = (const float*)d_in[6];
  const float* W2  = (const float*)d_in[7];
  const float* b2  = (const float*)d_in[8];
  const float* Wq  = (const float*)d_in[9];
  const float* Wo0 = (const float*)d_in[10];
  const float* Wo1 = (const float*)d_in[11];
  const float* Ws0 = (const float*)d_in[12];
  const float* Ws1 = (const float*)d_in[13];
  const float* bg  = (const float*)d_in[14];

  int N = in_sizes[0] / 3;
  int E = in_sizes[3];

  char* p = (char*)d_ws;
  auto alloc = [&](size_t bytes) {
    char* r = p;
    p += (bytes + 255) & ~(size_t)255;
    return r;
  };
  int* counts   = (int*)alloc((size_t)N * 4);
  int* offs     = (int*)alloc((size_t)(N + 1) * 4);
  int* cursor   = (int*)alloc((size_t)N * 4);
  int* bsums    = (int*)alloc(1024 * 4);
  int2* epkS    = (int2*)alloc((size_t)E * 8);
  float4* egeoS = (float4*)alloc((size_t)E * 16);
  float2* coef  = (float2*)alloc((size_t)5 * NIV * NCH * 8);
  float* tks    = (float*)alloc((size_t)5 * HRAD * 4);
  float4* fpk   = (float4*)alloc((size_t)N * CCH * 16);
  float4* Opk   = (float4*)alloc((size_t)N * CCH * 16);
  float* qbuf   = (float*)alloc((size_t)N * CCH * 4);
  int* bbase    = (int*)alloc((size_t)DG1 * 256 * 4);
  int* perm     = (int*)alloc((size_t)N * 4);

  int cpb = (N + DG1 - 1) / DG1;

  pwl_build_kernel<<<5 * NIV, 256, 0, stream>>>(W1, b1, W2, b2, coef, tks);
  hipMemsetAsync(counts, 0, (size_t)N * 4, stream);
  hist_kernel<<<(E + 255) / 256, 256, 0, stream>>>(dst, counts, E);
  deghistA_kernel<<<DG1, 256, 0, stream>>>(counts, bbase, N, cpb);
  int nb = (N + 1023) / 1024;
  scan1_kernel<<<nb, 1024, 0, stream>>>(counts, offs, bsums, N);
  scan2_kernel<<<1, 64, 0, stream>>>(bsums, nb);
  scan3_kernel<<<(N + 1 + 255) / 256, 256, 0, stream>>>(offs, bsums, cursor, N, E);
  degscanB_kernel<<<1, 256, 0, stream>>>(bbase);
  degscatC_kernel<<<DG1, 256, 0, stream>>>(counts, bbase, perm, N, cpb);
  scatter_kernel<<<(E + 255) / 256, 256, 0, stream>>>(pos, src, dst, cursor, tks,
                                                      epkS, egeoS, E);

  // log2(e) folded into the q pre-scale: softmax runs in exp2 domain.
  const float LOG2E = 1.4426950408889634f;
  float sc8 = LOG2E / sqrtf(8.0f);
  float sc32 = LOG2E / sqrtf(32.0f);
  int nblk = (N + ET - 1) / ET;
  pack_kernel<<<nblk, 512, 0, stream>>>(f0, f1, Wq, sc8, fpk, qbuf, N);

  float* out0 = (float*)d_out;
  float* out1 = out0 + (size_t)N * CCH;
  for (int l = 0; l < 5; l++) {
    bool last = (l == 4);
    if (last) {
      node_kernel<32><<<512, 1024, 0, stream>>>(
          fpk, qbuf, Opk, epkS, egeoS, offs, perm,
          coef + (size_t)l * NIV * NCH, 6 * l, N);
    } else {
      node_kernel<8><<<512, 1024, 0, stream>>>(
          fpk, qbuf, Opk, epkS, egeoS, offs, perm,
          coef + (size_t)l * NIV * NCH, 6 * l, N);
    }
    epi_kernel<<<nblk, 512, 0, stream>>>(
        Opk, fpk,
        Wo0 + l * CCH * CCH, Ws0 + l * CCH * CCH,
        Wo1 + l * CCH * CCH, Ws1 + l * CCH * CCH,
        bg + (last ? 0 : l) * CCH,
        Wq + (l + 1 <= 4 ? (l + 1) : 4) * CCH * CCH, qbuf,
        (l + 1 == 4) ? sc32 : sc8,
        out0, out1, last ? 1 : 0, N);
  }
}

// Round 10
// 756.183 us; speedup vs baseline: 1.1004x; 1.0777x over previous
//
#include <hip/hip_runtime.h>
#include <math.h>

#define CCH 32        // channels
#define NCH 224       // 7*C radial outputs
#define NIV 33        // PWL intervals
#define HRAD 32
#define ET 16         // nodes per epi block-iter
#define DG1 48        // blocks for degree counting sort (LDS-privatized)

// ---------------- CSR build ----------------

__global__ void hist_kernel(const int* __restrict__ dst, int* __restrict__ counts, int E) {
  int e = blockIdx.x * 256 + threadIdx.x;
  if (e < E) atomicAdd(&counts[dst[e]], 1);
}

__global__ void scan1_kernel(const int* __restrict__ counts, int* __restrict__ offs,
                             int* __restrict__ bsums, int n) {
  __shared__ int sd[1024];
  int t = threadIdx.x;
  int i = blockIdx.x * 1024 + t;
  int v = (i < n) ? counts[i] : 0;
  sd[t] = v;
  __syncthreads();
  for (int o = 1; o < 1024; o <<= 1) {
    int add = (t >= o) ? sd[t - o] : 0;
    __syncthreads();
    sd[t] += add;
    __syncthreads();
  }
  if (i < n) offs[i] = sd[t] - v;          // block-local exclusive
  if (t == 1023) bsums[blockIdx.x] = sd[1023];
}

__global__ void scan2_kernel(int* bsums, int nb) {
  if (threadIdx.x == 0 && blockIdx.x == 0) {
    int acc = 0;
    for (int i = 0; i < nb; i++) { int v = bsums[i]; bsums[i] = acc; acc += v; }
  }
}

__global__ void scan3_kernel(int* __restrict__ offs, const int* __restrict__ bsums,
                             int* __restrict__ cursor, int n, int E) {
  int i = blockIdx.x * 256 + threadIdx.x;
  if (i < n) {
    int v = offs[i] + bsums[i >> 10];
    offs[i] = v;
    cursor[i] = v;
  } else if (i == n) {
    offs[n] = E;
  }
}

// scatter precomputes, per edge, the PWL interval index for all 5 layers
// (same float compare as the original ballot, same stored rl, same unsorted
// kinks) packed 5x6 bits into epkS[].y; .x = src node.

__global__ void scatter_kernel(const float* __restrict__ pos, const int* __restrict__ src,
                               const int* __restrict__ dst, int* __restrict__ cursor,
                               const float* __restrict__ tksAll,
                               int2* __restrict__ epkS, float4* __restrict__ egeoS, int E) {
  __shared__ float sT[5 * HRAD];
  int t = threadIdx.x;
  if (t < 5 * HRAD) sT[t] = tksAll[t];
  __syncthreads();
  int e = blockIdx.x * 256 + t;
  if (e >= E) return;
  int s = src[e], d = dst[e];
  float rx = pos[d * 3 + 0] - pos[s * 3 + 0];
  float ry = pos[d * 3 + 1] - pos[s * 3 + 1];
  float rz = pos[d * 3 + 2] - pos[s * 3 + 2];
  float rl = sqrtf(rx * rx + ry * ry + rz * rz);
  float inv = 1.0f / (rl + 1e-6f);
  int ivpk = 0;
#pragma unroll
  for (int l = 0; l < 5; l++) {
    int cnt = 0;
#pragma unroll
    for (int k = 0; k < HRAD; k++) cnt += (rl > sT[l * HRAD + k]) ? 1 : 0;
    ivpk |= cnt << (6 * l);
  }
  int p = atomicAdd(&cursor[d], 1);
  epkS[p] = make_int2(s, ivpk);
  egeoS[p] = make_float4(rx * inv, ry * inv, rz * inv, rl);
}

// ---------------- degree-balanced schedule, contention-free build ----------------

__global__ void deghistA_kernel(const int* __restrict__ counts, int* __restrict__ bbase,
                                int n, int cpb) {
  __shared__ int lh[256];
  int t = threadIdx.x;
  lh[t] = 0;
  __syncthreads();
  int s = blockIdx.x * cpb, e = s + cpb; if (e > n) e = n;
  for (int i = s + t; i < e; i += 256) {
    int d = counts[i]; d = d > 255 ? 255 : d;
    atomicAdd(&lh[d], 1);
  }
  __syncthreads();
  bbase[blockIdx.x * 256 + t] = lh[t];
}

__global__ void degscanB_kernel(int* __restrict__ bbase) {
  __shared__ int sM[DG1 * 256];   // 48 KB
  __shared__ int gb[256];
  int t = threadIdx.x;            // 256 threads
  for (int i = t; i < DG1 * 256; i += 256) sM[i] = bbase[i];
  __syncthreads();
  int tot = 0;
  for (int b = 0; b < DG1; b++) tot += sM[b * 256 + t];
  gb[t] = tot;
  __syncthreads();
  if (t == 0) {                   // descending-degree exclusive scan
    int acc = 0;
    for (int d = 255; d >= 0; --d) { int v = gb[d]; gb[d] = acc; acc += v; }
  }
  __syncthreads();
  int run = gb[t];
  for (int b = 0; b < DG1; b++) { int v = sM[b * 256 + t]; sM[b * 256 + t] = run; run += v; }
  __syncthreads();
  for (int i = t; i < DG1 * 256; i += 256) bbase[i] = sM[i];
}

__global__ void degscatC_kernel(const int* __restrict__ counts, const int* __restrict__ bbase,
                                int* __restrict__ perm, int n, int cpb) {
  __shared__ int lc[256];
  int t = threadIdx.x;
  lc[t] = bbase[blockIdx.x * 256 + t];
  __syncthreads();
  int s = blockIdx.x * cpb, e = s + cpb; if (e > n) e = n;
  for (int i = s + t; i < e; i += 256) {
    int d = counts[i]; d = d > 255 ? 255 : d;
    int p = atomicAdd(&lc[d], 1);
    perm[p] = i;
  }
}

// ---------------- exact piecewise-linear collapse of the radial MLP ----------------

__global__ void pwl_build_kernel(const float* __restrict__ W1, const float* __restrict__ b1,
                                 const float* __restrict__ W2, const float* __restrict__ b2,
                                 float2* __restrict__ coef, float* __restrict__ tks) {
  int l = blockIdx.x / NIV;
  int iv = blockIdx.x - l * NIV;
  int tid = threadIdx.x;
  const float* w1 = W1 + l * HRAD;
  const float* bb1 = b1 + l * HRAD;
  const float* w2 = W2 + l * HRAD * NCH;
  const float* bb2 = b2 + l * NCH;
  __shared__ float a_s[HRAD], b_s[HRAD], t_s[HRAD], t_sorted[HRAD];
  if (tid < HRAD) {
    float a = w1[tid], b = bb1[tid];
    a_s[tid] = a; b_s[tid] = b;
    t_s[tid] = (a != 0.0f) ? (-b / a) : 1e30f;
  }
  __syncthreads();
  if (tid < HRAD) {
    float tj = t_s[tid];
    int rank = 0;
    for (int k = 0; k < HRAD; k++) {
      float tk = t_s[k];
      rank += (tk < tj) || (tk == tj && k < tid);
    }
    t_sorted[rank] = tj;
    if (iv == 0) tks[l * HRAD + tid] = tj;   // UNSORTED kinks (count-of-smaller is order-free)
  }
  __syncthreads();
  if (tid < NCH) {
    int k = tid;
    double lo = (iv == 0) ? (double)t_sorted[0] - 1.0 : (double)t_sorted[iv - 1];
    double hi = (iv == NIV - 1) ? (double)t_sorted[HRAD - 1] + 1.0 : (double)t_sorted[iv];
    double rm = 0.5 * (lo + hi);
    if (iv == 0) rm = (double)t_sorted[0] - 1.0;
    if (iv == NIV - 1) rm = (double)t_sorted[HRAD - 1] + 1.0;
    float alpha = bb2[k];
    float beta = 0.0f;
    for (int j = 0; j < HRAD; j++) {
      if ((double)a_s[j] * rm + (double)b_s[j] > 0.0) {
        float w = w2[j * NCH + k];
        alpha = fmaf(w, b_s[j], alpha);
        beta = fmaf(w, a_s[j], beta);
      }
    }
    // interleaved layout: [iv][c][path]
    coef[l * (NIV * NCH) + iv * NCH + (k & 31) * 7 + (k >> 5)] = make_float2(alpha, beta);
  }
}

// ---------------- initial pack (f0,f1 -> float4 rows) + q for layer 0 ----------------

__global__ __launch_bounds__(512) void pack_kernel(
    const float* __restrict__ f0, const float* __restrict__ f1,
    const float* __restrict__ Wq0, float scale0,
    float4* __restrict__ fpk, float* __restrict__ qbuf, int n) {
  __shared__ float sWq[1024];
  __shared__ float sF0[ET * 32];
  int tid = threadIdx.x;
  for (int i = tid; i < 1024; i += 512) sWq[i] = Wq0[i];
  __syncthreads();
  int nl = tid >> 5, c = tid & 31;
  for (int base = blockIdx.x * ET; base < n; base += gridDim.x * ET) {
    int node = base + nl;
    float v0 = 0.f, x = 0.f, y = 0.f, z = 0.f;
    if (node < n) {
      v0 = f0[(size_t)node * 32 + c];
      size_t b = ((size_t)node * 32 + c) * 3;
      x = f1[b]; y = f1[b + 1]; z = f1[b + 2];
      fpk[(size_t)node * 32 + c] = make_float4(v0, x, y, z);
    }
    sF0[nl * 32 + c] = v0;
    __syncthreads();
    if (node < n) {
      float q = 0.f;
#pragma unroll
      for (int k = 0; k < 32; k++) q = fmaf(sF0[nl * 32 + k], sWq[k * 32 + c], q);
      qbuf[(size_t)node * 32 + c] = q * scale0;
    }
    __syncthreads();
  }
}

// ---------------- per-node attention (softmax-weighted aggregation only) ----------------
// EMPIRICAL OPTIMUM (R7, node 85.0 us, total 753.7). DO NOT deepen the pipeline:
// R8 (depth-2 register rotation) = 100 us (waitcnt forced at the rotation movs);
// R9 (P/Q static-name unroll) = 96.8 us (prologue/epilogue overhead at deg~16,
// worse compiler schedule). At max residency (32 waves/CU) the loop is issue-
// slot-saturated + L2-miss-floored; depth-1 rotate + compiler scheduling wins.
//  * iv precomputed per edge in epkS[].y (5x6 bits); coef folded to 7 R-values
//    at prefetch time with that edge's r.
//  * serpentine degree-balanced schedule via perm; cross-node meta prefetch.
//  * no-max exp2-domain softmax (logits structurally tiny); DPP head-reduce.
//  * 32-bit indexing on fpk/qbuf/Opk.

template<int CTRL>
__device__ __forceinline__ float dpp_xor_add(float t) {
  return t + __int_as_float(__builtin_amdgcn_update_dpp(
      0, __float_as_int(t), CTRL, 0xF, 0xF, true));
}

template<int CH>
__global__ __launch_bounds__(1024) void node_kernel(
    const float4* __restrict__ fpk, const float* __restrict__ qbuf,
    float4* __restrict__ Opk,
    const int2* __restrict__ epkS, const float4* __restrict__ egeoS,
    const int* __restrict__ offs, const int* __restrict__ perm,
    const float2* __restrict__ coefG, int ivshift,
    int n) {
  __shared__ float2 sCoef[NIV * NCH];   // 59136 B
  int tid = threadIdx.x;
  for (int i = tid; i < NIV * NCH; i += 1024) sCoef[i] = coefG[i];
  __syncthreads();

  int lane = tid & 63;
  int wid = tid >> 6;
  int c = lane & 31;
  int half = lane >> 5;

  int W = gridDim.x * 16;
  int gw = blockIdx.x * 16 + wid;

  // serpentine positions for strata 0,1,2
  int pos0 = gw;
  int pos1 = 2 * W - 1 - gw;
  int pos2 = 2 * W + gw;
  int kk = 2;                       // stratum of pos2

  // ---- wave preamble: perm 2-deep, first node's metadata + first edge record ----
  int pcur = (pos0 < n) ? perm[pos0] : 0;
  int pnext = (pos1 < n) ? perm[pos1] : 0;
  int start = 0, end = 0;
  float qs = 0.f;
  int2 pe = make_int2(0, 0);
  float4 pg = make_float4(0, 0, 0, 0);
  if (pos0 < n) {
    start = offs[pcur];
    end = offs[pcur + 1];
    qs = qbuf[pcur * 32 + c];
    int j0 = start + half;
    if (j0 < end) { pe = epkS[j0]; pg = egeoS[j0]; }
  }

  for (; pos0 < n; ) {
    // ---- prefetch perm 2 ahead + NEXT node's metadata (hidden under edge loop) ----
    int pnn = (pos2 < n) ? perm[pos2] : 0;
    int nstart = 0, nend = 0;
    float nqs = 0.f;
    if (pos1 < n) {
      nstart = offs[pnext];
      nend = offs[pnext + 1];
      nqs = qbuf[pnext * 32 + c];
    }

    float z = 0.0f;
    float o0 = 0.0f, o10 = 0.0f, o11 = 0.0f, o12 = 0.0f;

    int j = start + half;

    // ---- stage first edge: F gather + coef->R fold (iv from the record) ----
    float4 g = pg;
    float4 F = make_float4(0, 0, 0, 0);
    float R0 = 0, R1 = 0, R2 = 0, R3 = 0, R4 = 0, R5 = 0, R6 = 0;
    int2 e1 = make_int2(0, 0);
    float4 g1 = make_float4(0, 0, 0, 0);
    if (j < end) {
      F = fpk[pe.x * 32 + c];
      int iv = (pe.y >> ivshift) & 63;
      const float2* cf = sCoef + (iv * 32 + c) * 7;
      float r = g.w;
      R0 = fmaf(cf[0].y, r, cf[0].x);
      R1 = fmaf(cf[1].y, r, cf[1].x);
      R2 = fmaf(cf[2].y, r, cf[2].x);
      R3 = fmaf(cf[3].y, r, cf[3].x);
      R4 = fmaf(cf[4].y, r, cf[4].x);
      R5 = fmaf(cf[5].y, r, cf[5].x);
      R6 = fmaf(cf[6].y, r, cf[6].x);
    }
    if (j + 2 < end) { e1 = epkS[j + 2]; g1 = egeoS[j + 2]; }

    while (j < end) {
      // snapshot current edge
      float4 gc = g;
      float4 Fc = F;
      float r0 = R0, r1 = R1, r2 = R2, r3 = R3, r4 = R4, r5 = R5, r6 = R6;
      int j2 = j + 2;
      if (j2 < end) {   // prefetch next edge: F gather + coef->R fold + next record
        F = fpk[e1.x * 32 + c];
        int iv = (e1.y >> ivshift) & 63;
        const float2* cf = sCoef + (iv * 32 + c) * 7;
        float r = g1.w;
        R0 = fmaf(cf[0].y, r, cf[0].x);
        R1 = fmaf(cf[1].y, r, cf[1].x);
        R2 = fmaf(cf[2].y, r, cf[2].x);
        R3 = fmaf(cf[3].y, r, cf[3].x);
        R4 = fmaf(cf[4].y, r, cf[4].x);
        R5 = fmaf(cf[5].y, r, cf[5].x);
        R6 = fmaf(cf[6].y, r, cf[6].x);
        g = g1;
        if (j2 + 2 < end) { e1 = epkS[j2 + 2]; g1 = egeoS[j2 + 2]; }
      }

      // ---- body: starts directly at dot1 (R ready) ----
      float dot1 = fmaf(Fc.y, gc.x, fmaf(Fc.z, gc.y, Fc.w * gc.z));
      float t = qs * fmaf(r0, Fc.x, r1 * dot1);
      // head-sum: VALU-only DPP butterfly (xor1, xor2, xor4-within-8)
      t = dpp_xor_add<0xB1>(t);    // quad_perm(1,0,3,2)
      t = dpp_xor_add<0x4E>(t);    // quad_perm(2,3,0,1)
      t = dpp_xor_add<0x141>(t);   // row_half_mirror == xor4 (quads uniform)
      if constexpr (CH == 32) {
        t = dpp_xor_add<0x140>(t); // row_mirror == xor8 (8-groups uniform)
        t = t + __int_as_float(__builtin_amdgcn_ds_swizzle(
                __float_as_int(t), 0x401F));   // xor16 within 32-lane half
      }
      float p = __builtin_amdgcn_exp2f(t);
      z += p;
      float v0 = fmaf(r2, Fc.x, r3 * dot1);
      float sg = fmaf(r5, Fc.x, r6 * dot1);
      o0  = fmaf(p, v0, o0);
      o10 = fmaf(p, fmaf(r4, Fc.y, sg * gc.x), o10);
      o11 = fmaf(p, fmaf(r4, Fc.z, sg * gc.y), o11);
      o12 = fmaf(p, fmaf(r4, Fc.w, sg * gc.z), o12);
      j = j2;
    }

    // ---- prefetch NEXT node's first edge record (nstart arrived long ago) ----
    pe = make_int2(0, 0);
    pg = make_float4(0, 0, 0, 0);
    if (pos1 < n) {
      int nj = nstart + half;
      if (nj < nend) { pe = epkS[nj]; pg = egeoS[nj]; }
    }

    // ---- merge the two half-wave states (plain sums) ----
    float zo  = __shfl_xor(z, 32, 64);
    float p0  = __shfl_xor(o0, 32, 64);
    float p10 = __shfl_xor(o10, 32, 64);
    float p11 = __shfl_xor(o11, 32, 64);
    float p12 = __shfl_xor(o12, 32, 64);
    float zf = z + zo;
    float inv = 1.0f / (zf + 1e-6f);
    if (!half) {
      Opk[pcur * 32 + c] = make_float4(
          (o0 + p0) * inv,
          (o10 + p10) * inv,
          (o11 + p11) * inv,
          (o12 + p12) * inv);
    }

    // ---- rotate node pipeline state (serpentine position step) ----
    pcur = pnext;
    pnext = pnn;
    start = nstart;
    end = nend;
    qs = nqs;
    pos0 = pos1;
    pos1 = pos2;
    ++kk;
    pos2 = kk * W + ((kk & 1) ? (W - 1 - gw) : gw);
  }
}

// ---------------- dense epilogue: out = O@Wo + f@Ws, NL, next-layer q ----------------

__global__ __launch_bounds__(512) void epi_kernel(
    const float4* __restrict__ Opk, float4* __restrict__ fpk,
    const float* __restrict__ Wo0G, const float* __restrict__ Ws0G,
    const float* __restrict__ Wo1G, const float* __restrict__ Ws1G,
    const float* __restrict__ bgG,
    const float* __restrict__ WqN, float* __restrict__ qbuf, float scaleN,
    float* __restrict__ out0, float* __restrict__ out1,
    int mode, int n) {
  __shared__ float4 sW[32 * 32];     // (wo0, ws0, wo1, ws1) 16 KB
  __shared__ float  sWq[32 * 32];    // 4 KB
  __shared__ float4 sO[ET * 32];     // 8 KB
  __shared__ float4 sF[ET * 32];     // 8 KB
  __shared__ float  sF0[ET * 32];    // 2 KB
  int tid = threadIdx.x;
  for (int i = tid; i < 1024; i += 512) {
    sW[i] = make_float4(Wo0G[i], Ws0G[i], Wo1G[i], Ws1G[i]);
    if (mode == 0) sWq[i] = WqN[i];
  }
  __syncthreads();
  int nl = tid >> 5;
  int c  = tid & 31;
  for (int base = blockIdx.x * ET; base < n; base += gridDim.x * ET) {
    int node = base + nl;
    bool valid = node < n;
    if (valid) {
      sO[tid] = Opk[(size_t)node * 32 + c];
      sF[tid] = fpk[(size_t)node * 32 + c];
    }
    __syncthreads();
    float a0 = 0.f, ax = 0.f, ay = 0.f, az = 0.f;
#pragma unroll
    for (int k = 0; k < 32; k++) {
      float4 O = sO[nl * 32 + k];
      float4 F = sF[nl * 32 + k];
      float4 w = sW[k * 32 + c];
      a0 = fmaf(O.x, w.x, fmaf(F.x, w.y, a0));
      ax = fmaf(O.y, w.z, fmaf(F.y, w.w, ax));
      ay = fmaf(O.z, w.z, fmaf(F.z, w.w, ay));
      az = fmaf(O.w, w.z, fmaf(F.w, w.w, az));
    }
    if (mode == 0) {
      float f0n = fmaxf(a0, 0.f);
      float n1 = sqrtf(fmaf(ax, ax, fmaf(ay, ay, az * az)));
      float gate = fmaxf(n1 + bgG[c], 0.f) / (n1 + 1e-6f);
      if (valid) fpk[(size_t)node * 32 + c] = make_float4(f0n, ax * gate, ay * gate, az * gate);
      sF0[nl * 32 + c] = f0n;
      __syncthreads();
      if (valid) {
        float q = 0.f;
#pragma unroll
        for (int k = 0; k < 32; k++) q = fmaf(sF0[nl * 32 + k], sWq[k * 32 + c], q);
        qbuf[(size_t)node * 32 + c] = q * scaleN;
      }
      __syncthreads();
    } else {
      if (valid) {
        out0[(size_t)node * 32 + c] = a0;
        size_t b = ((size_t)node * 32 + c) * 3;
        out1[b] = ax; out1[b + 1] = ay; out1[b + 2] = az;
      }
      __syncthreads();
    }
  }
}

// ---------------- host launch ----------------

extern "C" void kernel_launch(void* const* d_in, const int* in_sizes, int n_in,
                              void* d_out, int out_size, void* d_ws, size_t ws_size,
                              hipStream_t stream) {
  const float* pos = (const float*)d_in[0];
  const float* f0  = (const float*)d_in[1];
  const float* f1  = (const float*)d_in[2];
  const int* src   = (const int*)d_in[3];
  const int* dst   = (const int*)d_in[4];
  const float* W1  = (const float*)d_in[5];
  const float* b1  = (const float*)d_in[6];
  const float* W2  = (const float*)d_in[7];
  const float* b2  = (const float*)d_in[8];
  const float* Wq  = (const float*)d_in[9];
  const float* Wo0 = (const float*)d_in[10];
  const float* Wo1 = (const float*)d_in[11];
  const float* Ws0 = (const float*)d_in[12];
  const float* Ws1 = (const float*)d_in[13];
  const float* bg  = (const float*)d_in[14];

  int N = in_sizes[0] / 3;
  int E = in_sizes[3];

  char* p = (char*)d_ws;
  auto alloc = [&](size_t bytes) {
    char* r = p;
    p += (bytes + 255) & ~(size_t)255;
    return r;
  };
  int* counts   = (int*)alloc((size_t)N * 4);
  int* offs     = (int*)alloc((size_t)(N + 1) * 4);
  int* cursor   = (int*)alloc((size_t)N * 4);
  int* bsums    = (int*)alloc(1024 * 4);
  int2* epkS    = (int2*)alloc((size_t)E * 8);
  float4* egeoS = (float4*)alloc((size_t)E * 16);
  float2* coef  = (float2*)alloc((size_t)5 * NIV * NCH * 8);
  float* tks    = (float*)alloc((size_t)5 * HRAD * 4);
  float4* fpk   = (float4*)alloc((size_t)N * CCH * 16);
  float4* Opk   = (float4*)alloc((size_t)N * CCH * 16);
  float* qbuf   = (float*)alloc((size_t)N * CCH * 4);
  int* bbase    = (int*)alloc((size_t)DG1 * 256 * 4);
  int* perm     = (int*)alloc((size_t)N * 4);

  int cpb = (N + DG1 - 1) / DG1;

  pwl_build_kernel<<<5 * NIV, 256, 0, stream>>>(W1, b1, W2, b2, coef, tks);
  hipMemsetAsync(counts, 0, (size_t)N * 4, stream);
  hist_kernel<<<(E + 255) / 256, 256, 0, stream>>>(dst, counts, E);
  deghistA_kernel<<<DG1, 256, 0, stream>>>(counts, bbase, N, cpb);
  int nb = (N + 1023) / 1024;
  scan1_kernel<<<nb, 1024, 0, stream>>>(counts, offs, bsums, N);
  scan2_kernel<<<1, 64, 0, stream>>>(bsums, nb);
  scan3_kernel<<<(N + 1 + 255) / 256, 256, 0, stream>>>(offs, bsums, cursor, N, E);
  degscanB_kernel<<<1, 256, 0, stream>>>(bbase);
  degscatC_kernel<<<DG1, 256, 0, stream>>>(counts, bbase, perm, N, cpb);
  scatter_kernel<<<(E + 255) / 256, 256, 0, stream>>>(pos, src, dst, cursor, tks,
                                                      epkS, egeoS, E);

  // log2(e) folded into the q pre-scale: softmax runs in exp2 domain.
  const float LOG2E = 1.4426950408889634f;
  float sc8 = LOG2E / sqrtf(8.0f);
  float sc32 = LOG2E / sqrtf(32.0f);
  int nblk = (N + ET - 1) / ET;
  pack_kernel<<<nblk, 512, 0, stream>>>(f0, f1, Wq, sc8, fpk, qbuf, N);

  float* out0 = (float*)d_out;
  float* out1 = out0 + (size_t)N * CCH;
  for (int l = 0; l < 5; l++) {
    bool last = (l == 4);
    if (last) {
      node_kernel<32><<<512, 1024, 0, stream>>>(
          fpk, qbuf, Opk, epkS, egeoS, offs, perm,
          coef + (size_t)l * NIV * NCH, 6 * l, N);
    } else {
      node_kernel<8><<<512, 1024, 0, stream>>>(
          fpk, qbuf, Opk, epkS, egeoS, offs, perm,
          coef + (size_t)l * NIV * NCH, 6 * l, N);
    }
    epi_kernel<<<nblk, 512, 0, stream>>>(
        Opk, fpk,
        Wo0 + l * CCH * CCH, Ws0 + l * CCH * CCH,
        Wo1 + l * CCH * CCH, Ws1 + l * CCH * CCH,
        bg + (last ? 0 : l) * CCH,
        Wq + (l + 1 <= 4 ? (l + 1) : 4) * CCH * CCH, qbuf,
        (l + 1 == 4) ? sc32 : sc8,
        out0, out1, last ? 1 : 0, N);
  }
}